// Round 10
// baseline (103.006 us; speedup 1.0000x reference)
//
#include <hip/hip_runtime.h>
#include <hip/hip_bf16.h>

typedef short bf16x8 __attribute__((ext_vector_type(8)));
typedef __bf16 bfv8  __attribute__((ext_vector_type(8)));
typedef __bf16 bfv4  __attribute__((ext_vector_type(4)));
typedef float f32x4  __attribute__((ext_vector_type(4)));

#define S_LEN 4096
#define DDIM  64
#define KVB   32
#define QBLK  128               // q rows per block (4 waves x 32)
#define NHEAD 16
#define THR   7.0f              // defer-max threshold (log2 domain)
#define VOFFB 4096              // V^T region offset inside LDS buffer
#define BUFSZ 9216              // K tile 4096 B + V^T tile 64 rows x 80 B

#define MFMA(a, b, c) __builtin_amdgcn_mfma_f32_16x16x32_bf16((a), (b), (c), 0, 0, 0)

// base-2 exp via v_exp_f32 (avoid __exp2f: glibc macro collision)
static __device__ __forceinline__ float exp2v(float x) {
    return __builtin_amdgcn_exp2f(x);
}

// 8x fp32 -> bf16 RNE via native __bf16 casts (compiler fuses to v_cvt_pk_bf16_f32)
static __device__ __forceinline__ int4 cvt8(float4 a, float4 b) {
    bfv8 r;
    r[0] = (__bf16)a.x; r[1] = (__bf16)a.y; r[2] = (__bf16)a.z; r[3] = (__bf16)a.w;
    r[4] = (__bf16)b.x; r[5] = (__bf16)b.y; r[6] = (__bf16)b.z; r[7] = (__bf16)b.w;
    return __builtin_bit_cast(int4, r);
}
static __device__ __forceinline__ int2 cvt4(f32x4 a) {
    bfv4 r;
    r[0] = (__bf16)a[0]; r[1] = (__bf16)a[1]; r[2] = (__bf16)a[2]; r[3] = (__bf16)a[3];
    return __builtin_bit_cast(int2, r);
}

// K fragment read from row-major [32][64] bf16 LDS tile, XOR-swizzled
static __device__ __forceinline__ bf16x8 ldfrag(const unsigned char* base, int row, int doff) {
    int addr = (row * 128 + doff * 2) ^ ((row & 7) << 4);
    return *reinterpret_cast<const bf16x8*>(base + addr);
}

// stage one tile: K (linear copy of pre-swizzled block) + V^T (pad-stride copy)
static __device__ __forceinline__ void stage(unsigned char* base, int kdst, int vdst,
                                             int4 kv, int4 vv) {
    *reinterpret_cast<int4*>(base + kdst)         = kv;
    *reinterpret_cast<int4*>(base + VOFFB + vdst) = vv;
}

// online softmax for one 16-row q-set (base-2 domain) -> bf16 P operand,
// elements INTERLEAVED to match V^T's key layout: pos 2j <- key 4g+j, 2j+1 <- 16+4g+j.
// Common path: NO cross-lane ops (in-lane defer-max; l accumulated by ones-MFMA).
static __device__ __forceinline__ bf16x8 softmax_pb(f32x4 s0, f32x4 s1, float& m,
                                                    f32x4 acc[4], f32x4& lacc) {
    float mx = fmaxf(fmaxf(fmaxf(s0[0], s0[1]), s0[2]),
                     fmaxf(fmaxf(s0[3], s1[0]),
                           fmaxf(s1[1], fmaxf(s1[2], s1[3]))));
    if (!__all(mx <= m + THR)) {        // rare: true max grew past headroom
        float pm = fmaxf(mx, __shfl_xor(mx, 16));
        pm = fmaxf(pm, __shfl_xor(pm, 32));
        float mn = fmaxf(m, pm);
        float al = exp2v(m - mn);
        #pragma unroll
        for (int dk = 0; dk < 4; ++dk)
            #pragma unroll
            for (int j = 0; j < 4; ++j) acc[dk][j] *= al;
        #pragma unroll
        for (int j = 0; j < 4; ++j) lacc[j] *= al;
        m = mn;
    }
    bfv8 r;
    #pragma unroll
    for (int j = 0; j < 4; ++j) {
        r[2 * j]     = (__bf16)exp2v(s0[j] - m);
        r[2 * j + 1] = (__bf16)exp2v(s1[j] - m);
    }
    return __builtin_bit_cast(bf16x8, r);
}

// ---- pre-kernel: K -> bf16 pre-swizzled 4KB blocks; V -> V^T bf16 interleaved ----
__global__ __launch_bounds__(256) void prep(
    const float* __restrict__ Kg, const float* __restrict__ Vg,
    unsigned short* __restrict__ wsKT, unsigned short* __restrict__ wsVT)
{
    const int h  = blockIdx.y;
    const int kt = blockIdx.x;                 // 0..127
    const int t  = threadIdx.x;
    const int srow = t >> 3;
    const int sd   = (t & 7) * 8;
    const size_t src = (((size_t)h * S_LEN) + (size_t)kt * 32 + srow) * DDIM + sd;

    // K tile -> pre-swizzled bf16 block (byte image identical to attn LDS layout)
    {
        float4 a = *reinterpret_cast<const float4*>(Kg + src);
        float4 b = *reinterpret_cast<const float4*>(Kg + src + 4);
        const int swK = (srow * 128 + sd * 2) ^ ((srow & 7) << 4);
        *reinterpret_cast<int4*>(reinterpret_cast<char*>(wsKT)
            + ((size_t)(h * 128 + kt) << 12) + swK) = cvt8(a, b);
    }

    // V tile -> transpose+interleave via LDS
    __shared__ __align__(16) unsigned short vt[32][68];   // [key][d], padded stride
    {
        float4 a = *reinterpret_cast<const float4*>(Vg + src);
        float4 b = *reinterpret_cast<const float4*>(Vg + src + 4);
        int4 w = cvt8(a, b);
        int2 lo = {w.x, w.y}, hi = {w.z, w.w};
        *reinterpret_cast<int2*>(&vt[srow][sd])     = lo;
        *reinterpret_cast<int2*>(&vt[srow][sd + 4]) = hi;
    }
    __syncthreads();
    {
        const int d  = t >> 2;
        const int p0 = (t & 3) * 8;
        unsigned short out[8];
        #pragma unroll
        for (int i = 0; i < 8; ++i) {
            int p   = p0 + i;
            int key = 4 * (p >> 3) + ((p & 7) >> 1) + 16 * (p & 1);   // interleave map
            out[i] = vt[key][d];
        }
        *reinterpret_cast<int4*>(wsVT + ((size_t)(h * 128 + kt) * 2048) + d * 32 + p0)
            = *reinterpret_cast<const int4*>(out);
    }
}

template <int KSPLIT>
__global__ __launch_bounds__(256, 3) void attn_fwd(
    const float* __restrict__ Qg, const unsigned short* __restrict__ wsKT,
    const unsigned short* __restrict__ wsVT, float* __restrict__ Og,
    unsigned short* __restrict__ wsO, float* __restrict__ wsML)
{
    const int h    = blockIdx.y;
    const int qb   = blockIdx.x;
    const int ks   = (KSPLIT > 1) ? blockIdx.z : 0;
    int kt0, NT;
    if (KSPLIT == 3)      { kt0 = ks * 43; NT = (ks < 2) ? 43 : 42; }
    else if (KSPLIT == 2) { kt0 = ks * 64; NT = 64; }
    else                  { kt0 = 0;       NT = 128; }
    const int tid  = threadIdx.x;
    const int lane = tid & 63;
    const int wv   = tid >> 6;      // wave 0..3, each owns 32 q rows
    const int g    = lane >> 4;     // lane group 0..3
    const int r16  = lane & 15;

    __shared__ __align__(16) unsigned char lds[2 * BUFSZ];

    // ---- Q fragments: 2 sets of 16 rows, pre-scaled by log2(e)/sqrt(D) ----
    const float QSC = 0.125f * 1.44269504088896f;
    const int qrow0 = qb * QBLK + wv * 32 + r16;
    bf16x8 qf0[2], qf1[2];
    {
        const float* qp0 = Qg + ((size_t)h * S_LEN + qrow0) * DDIM;
        const float* qp1 = qp0 + 16 * DDIM;
        #pragma unroll
        for (int c = 0; c < 2; ++c) {
            float4 x = *reinterpret_cast<const float4*>(qp0 + 32 * c + 8 * g);
            float4 y = *reinterpret_cast<const float4*>(qp0 + 32 * c + 8 * g + 4);
            float4 xs = {x.x * QSC, x.y * QSC, x.z * QSC, x.w * QSC};
            float4 ys = {y.x * QSC, y.y * QSC, y.z * QSC, y.w * QSC};
            qf0[c] = __builtin_bit_cast(bf16x8, cvt8(xs, ys));
            x = *reinterpret_cast<const float4*>(qp1 + 32 * c + 8 * g);
            y = *reinterpret_cast<const float4*>(qp1 + 32 * c + 8 * g + 4);
            xs = {x.x * QSC, x.y * QSC, x.z * QSC, x.w * QSC};
            ys = {y.x * QSC, y.y * QSC, y.z * QSC, y.w * QSC};
            qf1[c] = __builtin_bit_cast(bf16x8, cvt8(xs, ys));
        }
    }

    bf16x8 ones;
    #pragma unroll
    for (int e = 0; e < 8; ++e) ones[e] = (short)0x3F80;

    // ---- staging: straight copies from pre-converted ws blocks ----
    const int kdst = tid * 16;                                  // K: linear byte copy
    const int vdst = (tid >> 2) * 80 + (tid & 3) * 16;          // V^T: 80B-stride rows
    const unsigned short* ktp = wsKT + ((size_t)(h * 128 + kt0) * 2048) + tid * 8;
    const unsigned short* vtp = wsVT + ((size_t)(h * 128 + kt0) * 2048)
                              + (tid >> 2) * 32 + (tid & 3) * 8;

    // prologue: tile 0 -> buf0; tile 1 -> regs
    int4 kv = *reinterpret_cast<const int4*>(ktp);
    int4 vv = *reinterpret_cast<const int4*>(vtp);
    stage(lds, kdst, vdst, kv, vv);
    ktp += 2048; vtp += 2048;
    kv = *reinterpret_cast<const int4*>(ktp);
    vv = *reinterpret_cast<const int4*>(vtp);
    __syncthreads();

    const f32x4 z0 = {0.f, 0.f, 0.f, 0.f};
    f32x4 accA[4] = {z0, z0, z0, z0};    // set0: d = 16dk+4g+j, q = r16
    f32x4 accB[4] = {z0, z0, z0, z0};    // set1: q = 16 + r16
    f32x4 laccA = z0, laccB = z0;        // running softmax denominators
    float m0 = -INFINITY, m1 = -INFINITY;

    int c = 0;
    for (int kt = 0; kt < NT; ++kt) {
        const unsigned char* Klds = lds + c * BUFSZ;
        const unsigned char* Vlds = Klds + VOFFB;

        // write next tile into other buffer; issue loads for tile kt+2
        if (kt + 1 < NT) {
            stage(lds + (c ^ 1) * BUFSZ, kdst, vdst, kv, vv);
            if (kt + 2 < NT) {
                ktp += 2048; vtp += 2048;
                kv = *reinterpret_cast<const int4*>(ktp);
                vv = *reinterpret_cast<const int4*>(vtp);
            }
        }

        // ---- V^T fragments: one b128 each, issued early (independent of scores) ----
        bf16x8 vf[4];
        {
            const unsigned char* vbase = Vlds + r16 * 80 + 16 * g;
            #pragma unroll
            for (int dk = 0; dk < 4; ++dk)
                vf[dk] = *reinterpret_cast<const bf16x8*>(vbase + dk * 1280);
        }

        // ---- QK^T (swapped): S^T tiles; keys 4g+j (+16), q = r16 ----
        f32x4 sA0 = z0, sA1 = z0, sB0 = z0, sB1 = z0;
        #pragma unroll
        for (int cc = 0; cc < 2; ++cc) {
            bf16x8 k0 = ldfrag(Klds, r16,      32 * cc + 8 * g);
            bf16x8 k1 = ldfrag(Klds, 16 + r16, 32 * cc + 8 * g);
            sA0 = MFMA(k0, qf0[cc], sA0);
            sA1 = MFMA(k1, qf0[cc], sA1);
            sB0 = MFMA(k0, qf1[cc], sB0);
            sB1 = MFMA(k1, qf1[cc], sB1);
        }

        // ---- softmax (interleaved P to match V^T key order) ----
        bf16x8 pbA = softmax_pb(sA0, sA1, m0, accA, laccA);
        bf16x8 pbB = softmax_pb(sB0, sB1, m1, accB, laccB);

        // ---- PV + denominator on the matrix pipe ----
        laccA = MFMA(ones, pbA, laccA);
        #pragma unroll
        for (int dk = 0; dk < 4; ++dk) accA[dk] = MFMA(vf[dk], pbA, accA[dk]);
        laccB = MFMA(ones, pbB, laccB);
        #pragma unroll
        for (int dk = 0; dk < 4; ++dk) accB[dk] = MFMA(vf[dk], pbB, accB[dk]);

        __syncthreads();
        c ^= 1;
    }

    // ---- epilogue (every lane holds the full denominator in lacc[0]) ----
    if (KSPLIT == 1) {
        float inv0 = 1.0f / laccA[0];
        float* op = Og + ((size_t)h * S_LEN + qrow0) * DDIM;
        #pragma unroll
        for (int dk = 0; dk < 4; ++dk) {
            float4 o = {accA[dk][0] * inv0, accA[dk][1] * inv0,
                        accA[dk][2] * inv0, accA[dk][3] * inv0};
            *reinterpret_cast<float4*>(op + 16 * dk + 4 * g) = o;
        }
        float inv1 = 1.0f / laccB[0];
        op += 16 * DDIM;
        #pragma unroll
        for (int dk = 0; dk < 4; ++dk) {
            float4 o = {accB[dk][0] * inv1, accB[dk][1] * inv1,
                        accB[dk][2] * inv1, accB[dk][3] * inv1};
            *reinterpret_cast<float4*>(op + 16 * dk + 4 * g) = o;
        }
    } else {
        // unnormalized bf16 partials + (m, l) per row
        const size_t R0 = (size_t)h * S_LEN + qrow0;
        unsigned short* o0 = wsO + ((size_t)ks * (NHEAD * S_LEN) + R0) * DDIM;
        #pragma unroll
        for (int dk = 0; dk < 4; ++dk)
            *reinterpret_cast<int2*>(o0 + 16 * dk + 4 * g) = cvt4(accA[dk]);
        o0 += 16 * DDIM;
        #pragma unroll
        for (int dk = 0; dk < 4; ++dk)
            *reinterpret_cast<int2*>(o0 + 16 * dk + 4 * g) = cvt4(accB[dk]);
        if (g == 0) {
            float2 v0 = {m0, laccA[0]};
            float2 v1 = {m1, laccB[0]};
            *reinterpret_cast<float2*>(wsML + ((size_t)ks * (NHEAD * S_LEN) + R0) * 2)      = v0;
            *reinterpret_cast<float2*>(wsML + ((size_t)ks * (NHEAD * S_LEN) + R0 + 16) * 2) = v1;
        }
    }
}

template <int NS>
__global__ __launch_bounds__(256) void combineN(
    const unsigned short* __restrict__ wsO, const float* __restrict__ wsML,
    float* __restrict__ Og)
{
    const int NR = NHEAD * S_LEN;
    int t  = blockIdx.x * 256 + threadIdx.x;     // one float4 of O per thread
    int R  = t >> 4;
    int d4 = (t & 15) * 4;
    float2 ml[NS];
    float m = -INFINITY;
    #pragma unroll
    for (int s = 0; s < NS; ++s) {
        ml[s] = *reinterpret_cast<const float2*>(wsML + ((size_t)s * NR + R) * 2);
        m = fmaxf(m, ml[s].x);
    }
    float a[NS], den = 0.f;
    #pragma unroll
    for (int s = 0; s < NS; ++s) { a[s] = exp2v(ml[s].x - m); den += a[s] * ml[s].y; }
    float inv = 1.0f / den;
    float4 o = {0.f, 0.f, 0.f, 0.f};
    #pragma unroll
    for (int s = 0; s < NS; ++s) {
        bfv4 ob = __builtin_bit_cast(bfv4,
            *reinterpret_cast<const int2*>(wsO + ((size_t)s * NR + R) * DDIM + d4));
        float w = a[s] * inv;
        o.x += w * (float)ob[0]; o.y += w * (float)ob[1];
        o.z += w * (float)ob[2]; o.w += w * (float)ob[3];
    }
    *reinterpret_cast<float4*>(Og + (size_t)R * DDIM + d4) = o;
}

extern "C" void kernel_launch(void* const* d_in, const int* in_sizes, int n_in,
                              void* d_out, int out_size, void* d_ws, size_t ws_size,
                              hipStream_t stream) {
    const float* Q = (const float*)d_in[0];
    const float* K = (const float*)d_in[1];
    const float* V = (const float*)d_in[2];
    float* O = (float*)d_out;

    const size_t nKT = (size_t)NHEAD * 128 * 2048;          // bf16 elems
    const size_t nVT = (size_t)NHEAD * 128 * 2048;
    const size_t nOrow = (size_t)NHEAD * S_LEN * DDIM;      // bf16 elems per split
    const size_t nMLrow = (size_t)NHEAD * S_LEN * 2;        // floats per split
    const size_t baseB  = (nKT + nVT) * 2;                  // 16,777,216
    const size_t perSplitB = nOrow * 2 + nMLrow * 4;        // 8,912,896
    const size_t need3 = baseB + 3 * perSplitB;             // 43,515,904
    const size_t need2 = baseB + 2 * perSplitB;             // 34,603,008 (proven fits)

    unsigned short* wsKT = (unsigned short*)d_ws;
    unsigned short* wsVT = wsKT + nKT;
    unsigned short* wsO  = wsVT + nVT;

    prep<<<dim3(128, NHEAD), dim3(256, 1, 1), 0, stream>>>(K, V, wsKT, wsVT);

    if (ws_size >= need3) {
        float* wsML = (float*)(wsO + 3 * nOrow);
        dim3 grid(S_LEN / QBLK, NHEAD, 3);
        attn_fwd<3><<<grid, dim3(256, 1, 1), 0, stream>>>(Q, wsKT, wsVT, O, wsO, wsML);
        int nthr = NHEAD * S_LEN * (DDIM / 4);
        combineN<3><<<dim3(nthr / 256), dim3(256, 1, 1), 0, stream>>>(wsO, wsML, O);
    } else if (ws_size >= need2) {
        float* wsML = (float*)(wsO + 2 * nOrow);
        dim3 grid(S_LEN / QBLK, NHEAD, 2);
        attn_fwd<2><<<grid, dim3(256, 1, 1), 0, stream>>>(Q, wsKT, wsVT, O, wsO, wsML);
        int nthr = NHEAD * S_LEN * (DDIM / 4);
        combineN<2><<<dim3(nthr / 256), dim3(256, 1, 1), 0, stream>>>(wsO, wsML, O);
    } else {
        dim3 grid(S_LEN / QBLK, NHEAD, 1);
        attn_fwd<1><<<grid, dim3(256, 1, 1), 0, stream>>>(Q, wsKT, wsVT, O, nullptr, nullptr);
    }
}

// Round 11
// 101.901 us; speedup vs baseline: 1.0108x; 1.0108x over previous
//
#include <hip/hip_runtime.h>
#include <hip/hip_bf16.h>

typedef short bf16x8 __attribute__((ext_vector_type(8)));
typedef __bf16 bfv8  __attribute__((ext_vector_type(8)));
typedef __bf16 bfv4  __attribute__((ext_vector_type(4)));
typedef float f32x4  __attribute__((ext_vector_type(4)));

#define S_LEN 4096
#define DDIM  64
#define KVB   32
#define QBLK  128               // q rows per block (4 waves x 32)
#define NHEAD 16
#define THR   7.0f              // defer-max threshold (log2 domain)
#define VOFFB 4096              // V^T region offset inside LDS buffer
#define BUFSZ 9216              // K tile 4096 B + V^T tile 64 rows x 80 B

#define MFMA(a, b, c) __builtin_amdgcn_mfma_f32_16x16x32_bf16((a), (b), (c), 0, 0, 0)

// base-2 exp via v_exp_f32 (avoid __exp2f: glibc macro collision)
static __device__ __forceinline__ float exp2v(float x) {
    return __builtin_amdgcn_exp2f(x);
}

// 8x fp32 -> bf16 RNE via native __bf16 casts (compiler fuses to v_cvt_pk_bf16_f32)
static __device__ __forceinline__ int4 cvt8(float4 a, float4 b) {
    bfv8 r;
    r[0] = (__bf16)a.x; r[1] = (__bf16)a.y; r[2] = (__bf16)a.z; r[3] = (__bf16)a.w;
    r[4] = (__bf16)b.x; r[5] = (__bf16)b.y; r[6] = (__bf16)b.z; r[7] = (__bf16)b.w;
    return __builtin_bit_cast(int4, r);
}
static __device__ __forceinline__ int2 cvt4(f32x4 a) {
    bfv4 r;
    r[0] = (__bf16)a[0]; r[1] = (__bf16)a[1]; r[2] = (__bf16)a[2]; r[3] = (__bf16)a[3];
    return __builtin_bit_cast(int2, r);
}

// K fragment read from row-major [32][64] bf16 LDS tile, XOR-swizzled
static __device__ __forceinline__ bf16x8 ldfrag(const unsigned char* base, int row, int doff) {
    int addr = (row * 128 + doff * 2) ^ ((row & 7) << 4);
    return *reinterpret_cast<const bf16x8*>(base + addr);
}

// stage one tile: K (linear copy of pre-swizzled block) + V^T (pad-stride copy)
static __device__ __forceinline__ void stage(unsigned char* base, int kdst, int vdst,
                                             int4 kv, int4 vv) {
    *reinterpret_cast<int4*>(base + kdst)         = kv;
    *reinterpret_cast<int4*>(base + VOFFB + vdst) = vv;
}

// online softmax for one 16-row q-set (base-2 domain) -> bf16 P operand,
// elements INTERLEAVED to match V^T's key layout: pos 2j <- key 4g+j, 2j+1 <- 16+4g+j.
// Common path: NO cross-lane ops (in-lane defer-max; l accumulated by ones-MFMA).
static __device__ __forceinline__ bf16x8 softmax_pb(f32x4 s0, f32x4 s1, float& m,
                                                    f32x4 acc[4], f32x4& lacc) {
    float mx = fmaxf(fmaxf(fmaxf(s0[0], s0[1]), s0[2]),
                     fmaxf(fmaxf(s0[3], s1[0]),
                           fmaxf(s1[1], fmaxf(s1[2], s1[3]))));
    if (!__all(mx <= m + THR)) {        // rare: true max grew past headroom
        float pm = fmaxf(mx, __shfl_xor(mx, 16));
        pm = fmaxf(pm, __shfl_xor(pm, 32));
        float mn = fmaxf(m, pm);
        float al = exp2v(m - mn);
        #pragma unroll
        for (int dk = 0; dk < 4; ++dk)
            #pragma unroll
            for (int j = 0; j < 4; ++j) acc[dk][j] *= al;
        #pragma unroll
        for (int j = 0; j < 4; ++j) lacc[j] *= al;
        m = mn;
    }
    bfv8 r;
    #pragma unroll
    for (int j = 0; j < 4; ++j) {
        r[2 * j]     = (__bf16)exp2v(s0[j] - m);
        r[2 * j + 1] = (__bf16)exp2v(s1[j] - m);
    }
    return __builtin_bit_cast(bf16x8, r);
}

// ---- pre-kernel: K -> bf16 pre-swizzled 4KB blocks; V -> V^T bf16 interleaved ----
__global__ __launch_bounds__(256) void prep(
    const float* __restrict__ Kg, const float* __restrict__ Vg,
    unsigned short* __restrict__ wsKT, unsigned short* __restrict__ wsVT)
{
    const int h  = blockIdx.y;
    const int kt = blockIdx.x;                 // 0..127
    const int t  = threadIdx.x;
    const int srow = t >> 3;
    const int sd   = (t & 7) * 8;
    const size_t src = (((size_t)h * S_LEN) + (size_t)kt * 32 + srow) * DDIM + sd;

    // K tile -> pre-swizzled bf16 block (byte image identical to attn LDS layout)
    {
        float4 a = *reinterpret_cast<const float4*>(Kg + src);
        float4 b = *reinterpret_cast<const float4*>(Kg + src + 4);
        const int swK = (srow * 128 + sd * 2) ^ ((srow & 7) << 4);
        *reinterpret_cast<int4*>(reinterpret_cast<char*>(wsKT)
            + ((size_t)(h * 128 + kt) << 12) + swK) = cvt8(a, b);
    }

    // V tile -> transpose+interleave via LDS
    __shared__ __align__(16) unsigned short vt[32][68];   // [key][d], padded stride
    {
        float4 a = *reinterpret_cast<const float4*>(Vg + src);
        float4 b = *reinterpret_cast<const float4*>(Vg + src + 4);
        int4 w = cvt8(a, b);
        int2 lo = {w.x, w.y}, hi = {w.z, w.w};
        *reinterpret_cast<int2*>(&vt[srow][sd])     = lo;
        *reinterpret_cast<int2*>(&vt[srow][sd + 4]) = hi;
    }
    __syncthreads();
    {
        const int d  = t >> 2;
        const int p0 = (t & 3) * 8;
        unsigned short out[8];
        #pragma unroll
        for (int i = 0; i < 8; ++i) {
            int p   = p0 + i;
            int key = 4 * (p >> 3) + ((p & 7) >> 1) + 16 * (p & 1);   // interleave map
            out[i] = vt[key][d];
        }
        *reinterpret_cast<int4*>(wsVT + ((size_t)(h * 128 + kt) * 2048) + d * 32 + p0)
            = *reinterpret_cast<const int4*>(out);
    }
}

template <int KSPLIT>
__global__ __launch_bounds__(256, 4) void attn_fwd(
    const float* __restrict__ Qg, const unsigned short* __restrict__ wsKT,
    const unsigned short* __restrict__ wsVT, float* __restrict__ Og,
    unsigned short* __restrict__ wsO, float* __restrict__ wsML)
{
    const int h    = blockIdx.y;
    const int qb   = blockIdx.x;
    const int ks   = (KSPLIT > 1) ? blockIdx.z : 0;
    const int kt0  = ks * (128 / KSPLIT);
    const int NT   = 128 / KSPLIT;
    const int tid  = threadIdx.x;
    const int lane = tid & 63;
    const int wv   = tid >> 6;      // wave 0..3, each owns 32 q rows
    const int g    = lane >> 4;     // lane group 0..3
    const int r16  = lane & 15;

    __shared__ __align__(16) unsigned char lds[2 * BUFSZ];

    // ---- Q fragments: 2 sets of 16 rows, pre-scaled by log2(e)/sqrt(D) ----
    const float QSC = 0.125f * 1.44269504088896f;
    const int qrow0 = qb * QBLK + wv * 32 + r16;
    bf16x8 qf0[2], qf1[2];
    {
        const float* qp0 = Qg + ((size_t)h * S_LEN + qrow0) * DDIM;
        const float* qp1 = qp0 + 16 * DDIM;
        #pragma unroll
        for (int c = 0; c < 2; ++c) {
            float4 x = *reinterpret_cast<const float4*>(qp0 + 32 * c + 8 * g);
            float4 y = *reinterpret_cast<const float4*>(qp0 + 32 * c + 8 * g + 4);
            float4 xs = {x.x * QSC, x.y * QSC, x.z * QSC, x.w * QSC};
            float4 ys = {y.x * QSC, y.y * QSC, y.z * QSC, y.w * QSC};
            qf0[c] = __builtin_bit_cast(bf16x8, cvt8(xs, ys));
            x = *reinterpret_cast<const float4*>(qp1 + 32 * c + 8 * g);
            y = *reinterpret_cast<const float4*>(qp1 + 32 * c + 8 * g + 4);
            xs = {x.x * QSC, x.y * QSC, x.z * QSC, x.w * QSC};
            ys = {y.x * QSC, y.y * QSC, y.z * QSC, y.w * QSC};
            qf1[c] = __builtin_bit_cast(bf16x8, cvt8(xs, ys));
        }
    }

    bf16x8 ones;
    #pragma unroll
    for (int e = 0; e < 8; ++e) ones[e] = (short)0x3F80;

    // ---- staging: straight copies from pre-converted ws blocks ----
    const int kdst = tid * 16;                                  // K: linear byte copy
    const int vdst = (tid >> 2) * 80 + (tid & 3) * 16;          // V^T: 80B-stride rows
    const unsigned short* ktp = wsKT + ((size_t)(h * 128 + kt0) * 2048) + tid * 8;
    const unsigned short* vtp = wsVT + ((size_t)(h * 128 + kt0) * 2048)
                              + (tid >> 2) * 32 + (tid & 3) * 8;

    // prologue: tile 0 -> buf0; tile 1 -> regs
    int4 kv = *reinterpret_cast<const int4*>(ktp);
    int4 vv = *reinterpret_cast<const int4*>(vtp);
    stage(lds, kdst, vdst, kv, vv);
    ktp += 2048; vtp += 2048;
    kv = *reinterpret_cast<const int4*>(ktp);
    vv = *reinterpret_cast<const int4*>(vtp);
    __syncthreads();

    const f32x4 z0 = {0.f, 0.f, 0.f, 0.f};
    f32x4 accA[4] = {z0, z0, z0, z0};    // set0: d = 16dk+4g+j, q = r16
    f32x4 accB[4] = {z0, z0, z0, z0};    // set1: q = 16 + r16
    f32x4 laccA = z0, laccB = z0;        // running softmax denominators
    float m0 = -INFINITY, m1 = -INFINITY;

    int c = 0;
    for (int kt = 0; kt < NT; ++kt) {
        const unsigned char* Klds = lds + c * BUFSZ;
        const unsigned char* Vlds = Klds + VOFFB;

        // write next tile into other buffer; issue loads for tile kt+2
        if (kt + 1 < NT) {
            stage(lds + (c ^ 1) * BUFSZ, kdst, vdst, kv, vv);
            if (kt + 2 < NT) {
                ktp += 2048; vtp += 2048;
                kv = *reinterpret_cast<const int4*>(ktp);
                vv = *reinterpret_cast<const int4*>(vtp);
            }
        }

        // ---- V^T fragments: one b128 each, issued early (independent of scores) ----
        bf16x8 vf[4];
        {
            const unsigned char* vbase = Vlds + r16 * 80 + 16 * g;
            #pragma unroll
            for (int dk = 0; dk < 4; ++dk)
                vf[dk] = *reinterpret_cast<const bf16x8*>(vbase + dk * 1280);
        }

        // ---- QK^T (swapped): S^T tiles; keys 4g+j (+16), q = r16 ----
        f32x4 sA0 = z0, sA1 = z0, sB0 = z0, sB1 = z0;
        #pragma unroll
        for (int cc = 0; cc < 2; ++cc) {
            bf16x8 k0 = ldfrag(Klds, r16,      32 * cc + 8 * g);
            bf16x8 k1 = ldfrag(Klds, 16 + r16, 32 * cc + 8 * g);
            sA0 = MFMA(k0, qf0[cc], sA0);
            sA1 = MFMA(k1, qf0[cc], sA1);
            sB0 = MFMA(k0, qf1[cc], sB0);
            sB1 = MFMA(k1, qf1[cc], sB1);
        }

        // ---- softmax (interleaved P to match V^T key order) ----
        bf16x8 pbA = softmax_pb(sA0, sA1, m0, accA, laccA);
        bf16x8 pbB = softmax_pb(sB0, sB1, m1, accB, laccB);

        // ---- PV + denominator on the matrix pipe ----
        laccA = MFMA(ones, pbA, laccA);
        #pragma unroll
        for (int dk = 0; dk < 4; ++dk) accA[dk] = MFMA(vf[dk], pbA, accA[dk]);
        laccB = MFMA(ones, pbB, laccB);
        #pragma unroll
        for (int dk = 0; dk < 4; ++dk) accB[dk] = MFMA(vf[dk], pbB, accB[dk]);

        __syncthreads();
        c ^= 1;
    }

    // ---- epilogue (every lane holds the full denominator in lacc[0]) ----
    if (KSPLIT == 1) {
        float inv0 = 1.0f / laccA[0];
        float* op = Og + ((size_t)h * S_LEN + qrow0) * DDIM;
        #pragma unroll
        for (int dk = 0; dk < 4; ++dk) {
            float4 o = {accA[dk][0] * inv0, accA[dk][1] * inv0,
                        accA[dk][2] * inv0, accA[dk][3] * inv0};
            *reinterpret_cast<float4*>(op + 16 * dk + 4 * g) = o;
        }
        float inv1 = 1.0f / laccB[0];
        op += 16 * DDIM;
        #pragma unroll
        for (int dk = 0; dk < 4; ++dk) {
            float4 o = {accB[dk][0] * inv1, accB[dk][1] * inv1,
                        accB[dk][2] * inv1, accB[dk][3] * inv1};
            *reinterpret_cast<float4*>(op + 16 * dk + 4 * g) = o;
        }
    } else {
        // unnormalized bf16 partials + (m, l) per row
        const size_t R0 = (size_t)h * S_LEN + qrow0;
        unsigned short* o0 = wsO + ((size_t)ks * (NHEAD * S_LEN) + R0) * DDIM;
        #pragma unroll
        for (int dk = 0; dk < 4; ++dk)
            *reinterpret_cast<int2*>(o0 + 16 * dk + 4 * g) = cvt4(accA[dk]);
        o0 += 16 * DDIM;
        #pragma unroll
        for (int dk = 0; dk < 4; ++dk)
            *reinterpret_cast<int2*>(o0 + 16 * dk + 4 * g) = cvt4(accB[dk]);
        if (g == 0) {
            float2 v0 = {m0, laccA[0]};
            float2 v1 = {m1, laccB[0]};
            *reinterpret_cast<float2*>(wsML + ((size_t)ks * (NHEAD * S_LEN) + R0) * 2)      = v0;
            *reinterpret_cast<float2*>(wsML + ((size_t)ks * (NHEAD * S_LEN) + R0 + 16) * 2) = v1;
        }
    }
}

template <int NS>
__global__ __launch_bounds__(256) void combineN(
    const unsigned short* __restrict__ wsO, const float* __restrict__ wsML,
    float* __restrict__ Og)
{
    const int NR = NHEAD * S_LEN;
    int t  = blockIdx.x * 256 + threadIdx.x;     // one float4 of O per thread
    int R  = t >> 4;
    int d4 = (t & 15) * 4;
    float2 ml[NS];
    float m = -INFINITY;
    #pragma unroll
    for (int s = 0; s < NS; ++s) {
        ml[s] = *reinterpret_cast<const float2*>(wsML + ((size_t)s * NR + R) * 2);
        m = fmaxf(m, ml[s].x);
    }
    float a[NS], den = 0.f;
    #pragma unroll
    for (int s = 0; s < NS; ++s) { a[s] = exp2v(ml[s].x - m); den += a[s] * ml[s].y; }
    float inv = 1.0f / den;
    float4 o = {0.f, 0.f, 0.f, 0.f};
    #pragma unroll
    for (int s = 0; s < NS; ++s) {
        bfv4 ob = __builtin_bit_cast(bfv4,
            *reinterpret_cast<const int2*>(wsO + ((size_t)s * NR + R) * DDIM + d4));
        float w = a[s] * inv;
        o.x += w * (float)ob[0]; o.y += w * (float)ob[1];
        o.z += w * (float)ob[2]; o.w += w * (float)ob[3];
    }
    *reinterpret_cast<float4*>(Og + (size_t)R * DDIM + d4) = o;
}

extern "C" void kernel_launch(void* const* d_in, const int* in_sizes, int n_in,
                              void* d_out, int out_size, void* d_ws, size_t ws_size,
                              hipStream_t stream) {
    const float* Q = (const float*)d_in[0];
    const float* K = (const float*)d_in[1];
    const float* V = (const float*)d_in[2];
    float* O = (float*)d_out;

    const size_t nKT = (size_t)NHEAD * 128 * 2048;          // bf16 elems
    const size_t nVT = (size_t)NHEAD * 128 * 2048;
    const size_t nOrow = (size_t)NHEAD * S_LEN * DDIM;      // bf16 elems per split
    const size_t nMLrow = (size_t)NHEAD * S_LEN * 2;        // floats per split
    const size_t baseB  = (nKT + nVT) * 2;                  // 16,777,216
    const size_t perSplitB = nOrow * 2 + nMLrow * 4;        // 8,912,896
    const size_t need2 = baseB + 2 * perSplitB;             // 34,603,008 (proven fits)

    unsigned short* wsKT = (unsigned short*)d_ws;
    unsigned short* wsVT = wsKT + nKT;
    unsigned short* wsO  = wsVT + nVT;

    prep<<<dim3(128, NHEAD), dim3(256, 1, 1), 0, stream>>>(K, V, wsKT, wsVT);

    if (ws_size >= need2) {
        float* wsML = (float*)(wsO + 2 * nOrow);
        dim3 grid(S_LEN / QBLK, NHEAD, 2);
        attn_fwd<2><<<grid, dim3(256, 1, 1), 0, stream>>>(Q, wsKT, wsVT, O, wsO, wsML);
        int nthr = NHEAD * S_LEN * (DDIM / 4);
        combineN<2><<<dim3(nthr / 256), dim3(256, 1, 1), 0, stream>>>(wsO, wsML, O);
    } else {
        dim3 grid(S_LEN / QBLK, NHEAD, 1);
        attn_fwd<1><<<grid, dim3(256, 1, 1), 0, stream>>>(Q, wsKT, wsVT, O, nullptr, nullptr);
    }
}